// Round 6
// baseline (265.395 us; speedup 1.0000x reference)
//
#include <hip/hip_runtime.h>

// GraphNorm: x[65536,512] f32, 128 graphs x 512 nodes.
// Full-chip 3-dispatch pipeline (round-3 fused version saturated per-CU BW
// but used only 128 CUs -> 36% of chip HBM peak).
//   k_stats    : 2048 blocks (16 slices/graph), per-slice S1/S2 partials -> ws
//   k_finalize : fold 32 partials + gnw/gnb/msc into per-(graph,dim) A,B
//   k_norm     : out = A*x + B; x re-read rides L3 (proven ~100% hit in r3),
//                nontemporal out-stores to avoid evicting x from L3.
// Ideal HBM traffic ~= 134 MB read + 134 MB write + ~34 MB partials ~= 48 us.
// (Resubmission: round-5 bench failed on container infra, kernel unevaluated.)

using f32x4 = __attribute__((ext_vector_type(4))) float;

constexpr int NUM_GRAPHS = 128;
constexpr int NPG        = 512;                  // nodes per graph
constexpr int D          = 512;
constexpr int D4         = D / 4;                // 128 float4 per row
constexpr int SLICES     = 16;                   // blocks per graph
constexpr int ROWS_PS    = NPG / SLICES;         // 32 rows per block
constexpr int RG         = 2;                    // row groups (256 thr / 128 cq)
constexpr int ROWS_PT    = ROWS_PS / RG;         // 16 rows per thread
constexpr float EPS      = 1e-6f;

// partials layout: part[block(2048)][rg(2)][k(2: S1,S2)][cq(128)] as f32x4
// = 16 MiB in ws. A,B follow: each NUM_GRAPHS*D4 f32x4 = 256 KiB.

// ---------------------------------------------------------------------------
__global__ __launch_bounds__(256) void k_stats(const float* __restrict__ x,
                                               f32x4* __restrict__ part) {
    const int b  = blockIdx.x;             // = g*SLICES + s; rows [32b, 32b+32)
    const int cq = threadIdx.x & (D4 - 1);
    const int rg = threadIdx.x >> 7;

    const f32x4* xp = reinterpret_cast<const f32x4*>(x)
                    + (size_t)b * ROWS_PS * D4 + (size_t)rg * D4 + cq;

    f32x4 s = {0.f, 0.f, 0.f, 0.f};
    f32x4 q = {0.f, 0.f, 0.f, 0.f};
    #pragma unroll
    for (int i = 0; i < ROWS_PT; ++i) {
        f32x4 v = xp[(size_t)i * RG * D4];
        s += v;
        q += v * v;            // contracted to fma by the compiler
    }

    f32x4* p = part + (((size_t)b * RG + rg) * 2) * D4 + cq;
    p[0]  = s;                 // S1
    p[D4] = q;                 // S2
}

// ---------------------------------------------------------------------------
__device__ inline float2 finalize1(float s1, float s2, float w, float bi,
                                   float ms) {
    const float inv_n = 1.0f / (float)NPG;
    const float m = s1 * inv_n;
    const float c = m * ms;
    float var = fmaxf(fmaf(c, c, fmaf(-2.f * c, m, s2 * inv_n)), 0.f);
    const float r = rsqrtf(var + EPS);
    const float A = w * r;
    const float B = fmaf(-A, c, bi);
    return make_float2(A, B);
}

__global__ __launch_bounds__(256) void k_finalize(const f32x4* __restrict__ part,
                                                  const float* __restrict__ gnw,
                                                  const float* __restrict__ gnb,
                                                  const float* __restrict__ msc,
                                                  f32x4* __restrict__ Aa,
                                                  f32x4* __restrict__ Ba) {
    const int idx = blockIdx.x * 256 + threadIdx.x;   // 0 .. 16383
    const int g   = idx >> 7;                          // graph
    const int cq  = idx & (D4 - 1);                    // dim quad

    f32x4 S1 = {0.f, 0.f, 0.f, 0.f};
    f32x4 S2 = {0.f, 0.f, 0.f, 0.f};
    #pragma unroll
    for (int sl = 0; sl < SLICES; ++sl) {
        #pragma unroll
        for (int rg = 0; rg < RG; ++rg) {
            const f32x4* p = part
                + (((size_t)(g * SLICES + sl) * RG + rg) * 2) * D4 + cq;
            S1 += p[0];
            S2 += p[D4];
        }
    }

    const f32x4 w4 = reinterpret_cast<const f32x4*>(gnw)[cq];
    const f32x4 b4 = reinterpret_cast<const f32x4*>(gnb)[cq];
    const f32x4 m4 = reinterpret_cast<const f32x4*>(msc)[cq];
    f32x4 A, B;
    float2 r;
    r = finalize1(S1.x, S2.x, w4.x, b4.x, m4.x); A.x = r.x; B.x = r.y;
    r = finalize1(S1.y, S2.y, w4.y, b4.y, m4.y); A.y = r.x; B.y = r.y;
    r = finalize1(S1.z, S2.z, w4.z, b4.z, m4.z); A.z = r.x; B.z = r.y;
    r = finalize1(S1.w, S2.w, w4.w, b4.w, m4.w); A.w = r.x; B.w = r.y;

    Aa[(size_t)g * D4 + cq] = A;
    Ba[(size_t)g * D4 + cq] = B;
}

// ---------------------------------------------------------------------------
__global__ __launch_bounds__(256) void k_norm(const float* __restrict__ x,
                                              const f32x4* __restrict__ Aa,
                                              const f32x4* __restrict__ Ba,
                                              float* __restrict__ out) {
    const int b  = blockIdx.x;             // rows [32b, 32b+32), graph b>>4
    const int g  = b >> 4;
    const int cq = threadIdx.x & (D4 - 1);
    const int rg = threadIdx.x >> 7;

    const f32x4 a  = Aa[(size_t)g * D4 + cq];
    const f32x4 bb = Ba[(size_t)g * D4 + cq];

    const size_t base = (size_t)b * ROWS_PS * D4 + (size_t)rg * D4 + cq;
    const f32x4* xp = reinterpret_cast<const f32x4*>(x) + base;
    f32x4*       op = reinterpret_cast<f32x4*>(out) + base;

    #pragma unroll
    for (int i = 0; i < ROWS_PT; ++i) {
        f32x4 v = xp[(size_t)i * RG * D4];
        f32x4 r = a * v + bb;              // fma-contracted
        __builtin_nontemporal_store(r, &op[(size_t)i * RG * D4]);
    }
}

// ---------------------------------------------------------------------------
extern "C" void kernel_launch(void* const* d_in, const int* in_sizes, int n_in,
                              void* d_out, int out_size, void* d_ws, size_t ws_size,
                              hipStream_t stream) {
    const float* x   = (const float*)d_in[0];
    const float* gnw = (const float*)d_in[1];
    const float* gnb = (const float*)d_in[2];
    const float* msc = (const float*)d_in[3];
    // d_in[4] = batch_num: uniform NPG per harness setup; unused.
    float* out = (float*)d_out;

    f32x4* part = (f32x4*)d_ws;                                   // 16 MiB
    f32x4* Aa   = part + (size_t)NUM_GRAPHS * SLICES * RG * 2 * D4;
    f32x4* Ba   = Aa + (size_t)NUM_GRAPHS * D4;

    k_stats   <<<NUM_GRAPHS * SLICES, 256, 0, stream>>>(x, part);
    k_finalize<<<(NUM_GRAPHS * D4) / 256, 256, 0, stream>>>(part, gnw, gnb,
                                                            msc, Aa, Ba);
    k_norm    <<<NUM_GRAPHS * SLICES, 256, 0, stream>>>(x, Aa, Ba, out);
}